// Round 5
// baseline (95.447 us; speedup 1.0000x reference)
//
#include <hip/hip_runtime.h>
#include <hip/hip_bf16.h>

#define B_ 64
#define S_ 128
#define D_ 1024
#define O_ 1024
#define L_ 16

typedef __bf16 bf16x8 __attribute__((ext_vector_type(8)));
typedef float f32x4 __attribute__((ext_vector_type(4)));

// ws layout (bytes):
//  [0, 33554432)        W bf16, tiles [l][nt8:8][kt:16], each 128(o) x 64(k) bf16 = 16384 B, XOR-swizzled
//  [33554432, 50331648) x bf16, tiles [s:128][kt:16], each 64(b) x 64(k) bf16 = 8192 B, XOR-swizzled
//  [50331648]           npairs (int, 16-byte slot)
//  [50331664, +72*16)   pairs int4 {s0, s1, layer, 0}
#define WS_W   0ull
#define WS_X   33554432ull
#define WS_P   50331648ull
#define WS_NEED (50331664ull + 72ull * 16ull)

__device__ __forceinline__ unsigned f2bf2(float a, float b) {
    union { float f; unsigned u; } x{a}, y{b};
    unsigned lo = x.u + 0x7FFFu + ((x.u >> 16) & 1u);
    unsigned hi = y.u + 0x7FFFu + ((y.u >> 16) & 1u);
    return (lo >> 16) | (hi & 0xFFFF0000u);
}

__device__ __forceinline__ void gload16(const void* g, void* l) {
    __builtin_amdgcn_global_load_lds(
        (const __attribute__((address_space(1))) void*)g,
        (__attribute__((address_space(3))) void*)l, 16, 0, 0);
}

// ---- pass 1: fp32 -> bf16 conversion into pre-swizzled tiles + pair build ----
__global__ __launch_bounds__(256) void moshi_convert(
    const float* __restrict__ x, const float* __restrict__ w,
    const int* __restrict__ lidx, unsigned char* __restrict__ ws) {
    if (blockIdx.x == 0 && threadIdx.x < 16) {
        int t = threadIdx.x;
        int cnt[16];
        #pragma unroll 1
        for (int m = 0; m < 16; ++m) cnt[m] = 0;
        for (int s = 0; s < S_; ++s) ++cnt[lidx[s]];
        int off = 0;
        for (int m = 0; m < t; ++m) off += (cnt[m] + 1) >> 1;
        int4* pairs = (int4*)(ws + WS_P + 16);
        int k = 0, prev = -1;
        for (int s = 0; s < S_; ++s) {
            if (lidx[s] == t) {
                if (k & 1) pairs[off + (k >> 1)] = make_int4(prev, s, t, 0);
                prev = s; ++k;
            }
        }
        if (k & 1) pairs[off + (k >> 1)] = make_int4(prev, prev, t, 0);
        if (t == 0) {
            int tot = 0;
            for (int m = 0; m < 16; ++m) tot += (cnt[m] + 1) >> 1;
            *(int*)(ws + WS_P) = tot;
        }
    }
    const int TW = L_ * O_ * D_ / 4;
    const int TX = B_ * S_ * D_ / 4;
    for (int f = blockIdx.x * 256 + threadIdx.x; f < TW + TX; f += gridDim.x * 256) {
        if (f < TW) {
            const float4 v = *reinterpret_cast<const float4*>(w + 4ull * f);
            uint2 pk = { f2bf2(v.x, v.y), f2bf2(v.z, v.w) };
            int d4 = f & 255, o = (f >> 8) & 1023, l = f >> 18;
            int nt = o >> 7, row = o & 127, kt = d4 >> 4;
            unsigned byte = ((unsigned)((l * 8 + nt) * 16 + kt)) * 16384u
                          + (((unsigned)(row * 128 + (d4 & 15) * 8)) ^ ((row & 7) << 4));
            *reinterpret_cast<uint2*>(ws + WS_W + byte) = pk;
        } else {
            int g = f - TW;
            const float4 v = *reinterpret_cast<const float4*>(x + 4ull * g);
            uint2 pk = { f2bf2(v.x, v.y), f2bf2(v.z, v.w) };
            int d4 = g & 255, s = (g >> 8) & 127, b = g >> 15;
            int kt = d4 >> 4;
            unsigned byte = ((unsigned)(s * 16 + kt)) * 8192u
                          + (((unsigned)(b * 128 + (d4 & 15) * 8)) ^ ((b & 7) << 4));
            *reinterpret_cast<uint2*>(ws + WS_X + byte) = pk;
        }
    }
}

// ---- shared block-setup for the 128x64-tile kernels ----
struct TileCtx {
    const unsigned char* wt;
    const unsigned char* xt0;
    const unsigned char* xt1;
    int s0, s1, nt;
    int a_base, b_base, swz;
    int tid, lane, wid, wm, wn;
    bool active;
};

__device__ __forceinline__ TileCtx tile_setup(const unsigned char* ws) {
    TileCtx c;
    // bijective XCD-chunk swizzle: grid 1152 = 8 chunks of 144 (9 pairs x 16 nt)
    const int bid = (blockIdx.x & 7) * 144 + (blockIdx.x >> 3);
    const int pi = bid >> 4;
    c.nt = bid & 15;
    const int np = *reinterpret_cast<const int*>(ws + WS_P);
    c.active = (pi < np);
    if (!c.active) return c;
    const int4 pr = *reinterpret_cast<const int4*>(ws + WS_P + 16 + 16ull * pi);
    c.s0 = pr.x; c.s1 = pr.y;
    const int l = pr.z;
    c.wt  = ws + WS_W + ((size_t)(l * 8 + (c.nt >> 1)) * 16) * 16384 + (size_t)(c.nt & 1) * 8192;
    c.xt0 = ws + WS_X + (size_t)c.s0 * 16 * 8192;
    c.xt1 = ws + WS_X + (size_t)c.s1 * 16 * 8192;
    c.tid = threadIdx.x; c.lane = c.tid & 63; c.wid = c.tid >> 6;
    c.wm = c.wid >> 1; c.wn = c.wid & 1;
    c.swz = (c.lane & 7) << 4;
    const int kb = (c.lane >> 4) << 4;
    c.a_base = (c.wm * 64 + (c.lane & 15)) * 128 + kb;
    c.b_base = (c.wn * 32 + (c.lane & 15)) * 128 + kb;
    return c;
}

// stage one K-tile: W half-tile 8KB (2 gloads) + two x tiles 8KB each (4 gloads)
__device__ __forceinline__ void tile_stage(const TileCtx& c, int kt,
                                           unsigned char* lw, unsigned char* lx) {
    gload16(c.wt + (size_t)kt * 16384 + c.tid * 16,          lw + c.tid * 16);
    gload16(c.wt + (size_t)kt * 16384 + c.tid * 16 + 4096,   lw + c.tid * 16 + 4096);
    gload16(c.xt0 + (size_t)kt * 8192 + c.tid * 16,          lx + c.tid * 16);
    gload16(c.xt0 + (size_t)kt * 8192 + c.tid * 16 + 4096,   lx + c.tid * 16 + 4096);
    gload16(c.xt1 + (size_t)kt * 8192 + c.tid * 16,          lx + 8192 + c.tid * 16);
    gload16(c.xt1 + (size_t)kt * 8192 + c.tid * 16 + 4096,   lx + 8192 + c.tid * 16 + 4096);
}

// ---- pass 2 (REAL): paired GEMM, tile M=128 (2s x 64b), N=64, BK=64.
// 4 waves (2 wm x 2 wn), each wave 64x32 = 4x2 fragments. Single-buffer
// 2-barrier loop (R2 structure), 24 KB LDS -> ~4-6 blocks/CU resident.
__global__ __launch_bounds__(256) void moshi_gemm_n64(
    const unsigned char* __restrict__ ws, float* __restrict__ out) {
    __shared__ __align__(16) unsigned char lw[8192];
    __shared__ __align__(16) unsigned char lx[16384];
    TileCtx c = tile_setup(ws);
    if (!c.active) return;

    f32x4 acc[4][2];
    #pragma unroll
    for (int i = 0; i < 4; ++i)
        #pragma unroll
        for (int j = 0; j < 2; ++j) acc[i][j] = (f32x4)0.0f;

    #pragma unroll 1
    for (int kt = 0; kt < 16; ++kt) {
        __syncthreads();
        tile_stage(c, kt, lw, lx);
        __syncthreads();
        #pragma unroll
        for (int kk = 0; kk < 2; ++kk) {
            bf16x8 af[4], bfr[2];
            #pragma unroll
            for (int mi = 0; mi < 4; ++mi)
                af[mi] = *reinterpret_cast<const bf16x8*>(
                    lx + (((c.a_base + kk * 64) ^ c.swz) + mi * 2048));
            #pragma unroll
            for (int ni = 0; ni < 2; ++ni)
                bfr[ni] = *reinterpret_cast<const bf16x8*>(
                    lw + (((c.b_base + kk * 64) ^ c.swz) + ni * 2048));
            #pragma unroll
            for (int mi = 0; mi < 4; ++mi)
                #pragma unroll
                for (int ni = 0; ni < 2; ++ni)
                    acc[mi][ni] = __builtin_amdgcn_mfma_f32_16x16x32_bf16(
                        af[mi], bfr[ni], acc[mi][ni], 0, 0, 0);
        }
    }

    const int s_sel = c.wm ? c.s1 : c.s0;
    const int col0 = c.nt * 64 + c.wn * 32 + (c.lane & 15);
    const int r0 = (c.lane >> 4) << 2;
    #pragma unroll
    for (int mi = 0; mi < 4; ++mi)
        #pragma unroll
        for (int ni = 0; ni < 2; ++ni)
            #pragma unroll
            for (int r = 0; r < 4; ++r) {
                int b = mi * 16 + r0 + r;
                out[((size_t)b * S_ + s_sel) * O_ + col0 + ni * 16] = acc[mi][ni][r];
            }
}

// ---- diagnostics (launched BEFORE the real gemm; real gemm overwrites all of out).
// MODE 1: staging + barriers only. MODE 2: ds_read + MFMA + barriers only.
template <int MODE>
__global__ __launch_bounds__(256) void moshi_diag(
    const unsigned char* __restrict__ ws, float* __restrict__ out) {
    __shared__ __align__(16) unsigned char lw[8192];
    __shared__ __align__(16) unsigned char lx[16384];
    TileCtx c = tile_setup(ws);
    if (!c.active) return;

    f32x4 acc[4][2];
    #pragma unroll
    for (int i = 0; i < 4; ++i)
        #pragma unroll
        for (int j = 0; j < 2; ++j) acc[i][j] = (f32x4)0.0f;

    if (MODE == 2) {               // stage once, then compute-only loop
        tile_stage(c, 0, lw, lx);
        __syncthreads();
    }

    #pragma unroll 1
    for (int kt = 0; kt < 16; ++kt) {
        if (MODE == 1) {
            __syncthreads();
            tile_stage(c, kt, lw, lx);
            __syncthreads();
        } else {
            // launder bases so ds_reads can't be hoisted out of the loop
            int ab = c.a_base, bb = c.b_base;
            asm volatile("" : "+v"(ab), "+v"(bb));
            #pragma unroll
            for (int kk = 0; kk < 2; ++kk) {
                bf16x8 af[4], bfr[2];
                #pragma unroll
                for (int mi = 0; mi < 4; ++mi)
                    af[mi] = *reinterpret_cast<const bf16x8*>(
                        lx + (((ab + kk * 64) ^ c.swz) + mi * 2048));
                #pragma unroll
                for (int ni = 0; ni < 2; ++ni)
                    bfr[ni] = *reinterpret_cast<const bf16x8*>(
                        lw + (((bb + kk * 64) ^ c.swz) + ni * 2048));
                #pragma unroll
                for (int mi = 0; mi < 4; ++mi)
                    #pragma unroll
                    for (int ni = 0; ni < 2; ++ni)
                        acc[mi][ni] = __builtin_amdgcn_mfma_f32_16x16x32_bf16(
                            af[mi], bfr[ni], acc[mi][ni], 0, 0, 0);
            }
            __syncthreads();
        }
    }

    // keep results live; real gemm overwrites every element of out afterwards
    if (MODE == 1) {
        out[(size_t)blockIdx.x * 256 + c.tid] = 1.0f;
    } else {
        float v = 0.f;
        #pragma unroll
        for (int mi = 0; mi < 4; ++mi)
            #pragma unroll
            for (int ni = 0; ni < 2; ++ni)
                v += acc[mi][ni][0] + acc[mi][ni][3];
        out[(size_t)blockIdx.x * 256 + c.tid] = v;
    }
}

// ---- fallback (round-1 kernel) if ws is too small ----
__global__ __launch_bounds__(256) void moshi_flin_fallback(
    const float* __restrict__ x, const int* __restrict__ lidx,
    const float* __restrict__ w, float* __restrict__ out) {
    __shared__ __align__(16) unsigned char lxs[64 * 128];
    __shared__ __align__(16) unsigned char lws[128 * 128];
    const int bid = blockIdx.x;
    const int s = bid >> 3, n0 = (bid & 7) << 7;
    const int tid = threadIdx.x, lane = tid & 63, wid = tid >> 6;
    const int idx = lidx[s];
    const float* wb = w + (size_t)idx * O_ * D_ + (size_t)n0 * D_;
    const float* xb = x + (size_t)s * D_;
    const int swz = (lane & 7) << 4;
    const int kb = (lane >> 4) << 4;
    const int a_base = (lane & 15) * 128 + kb;
    const int b_base = (wid * 32 + (lane & 15)) * 128 + kb;
    f32x4 acc[4][2];
    #pragma unroll
    for (int i = 0; i < 4; ++i)
        #pragma unroll
        for (int j = 0; j < 2; ++j) acc[i][j] = (f32x4)0.0f;
    for (int kt = 0; kt < D_; kt += 64) {
        __syncthreads();
        #pragma unroll
        for (int p = 0; p < 4; ++p) {
            int f = tid + p * 256, row = f >> 4, cc = (f & 15) << 2;
            const float4 v = *reinterpret_cast<const float4*>(
                xb + (size_t)row * (S_ * D_) + kt + cc);
            uint2 pk = { f2bf2(v.x, v.y), f2bf2(v.z, v.w) };
            *reinterpret_cast<uint2*>(&lxs[(row * 128 + cc * 2) ^ ((row & 7) << 4)]) = pk;
        }
        #pragma unroll
        for (int p = 0; p < 8; ++p) {
            int f = tid + p * 256, row = f >> 4, cc = (f & 15) << 2;
            const float4 v = *reinterpret_cast<const float4*>(
                wb + (size_t)row * D_ + kt + cc);
            uint2 pk = { f2bf2(v.x, v.y), f2bf2(v.z, v.w) };
            *reinterpret_cast<uint2*>(&lws[(row * 128 + cc * 2) ^ ((row & 7) << 4)]) = pk;
        }
        __syncthreads();
        #pragma unroll
        for (int kk = 0; kk < 2; ++kk) {
            bf16x8 af[4], bfr[2];
            #pragma unroll
            for (int mi = 0; mi < 4; ++mi)
                af[mi] = *reinterpret_cast<const bf16x8*>(
                    &lxs[(((a_base + kk * 64) ^ swz) + mi * 2048)]);
            #pragma unroll
            for (int ni = 0; ni < 2; ++ni)
                bfr[ni] = *reinterpret_cast<const bf16x8*>(
                    &lws[(((b_base + kk * 64) ^ swz) + ni * 2048)]);
            #pragma unroll
            for (int mi = 0; mi < 4; ++mi)
                #pragma unroll
                for (int ni = 0; ni < 2; ++ni)
                    acc[mi][ni] = __builtin_amdgcn_mfma_f32_16x16x32_bf16(
                        af[mi], bfr[ni], acc[mi][ni], 0, 0, 0);
        }
    }
    float* ob = out + (size_t)s * O_ + n0 + wid * 32 + (lane & 15);
    const int r0 = (lane >> 4) << 2;
    #pragma unroll
    for (int mi = 0; mi < 4; ++mi)
        #pragma unroll
        for (int ni = 0; ni < 2; ++ni)
            #pragma unroll
            for (int r = 0; r < 4; ++r) {
                int b = mi * 16 + r0 + r;
                ob[(size_t)b * (S_ * O_) + ni * 16] = acc[mi][ni][r];
            }
}

extern "C" void kernel_launch(void* const* d_in, const int* in_sizes, int n_in,
                              void* d_out, int out_size, void* d_ws, size_t ws_size,
                              hipStream_t stream) {
    const float* x  = (const float*)d_in[0];
    const int* lidx = (const int*)d_in[1];
    const float* w  = (const float*)d_in[2];
    float* out      = (float*)d_out;

    if (ws_size < WS_NEED) {
        moshi_flin_fallback<<<dim3(128 * 8), dim3(256), 0, stream>>>(x, lidx, w, out);
        return;
    }
    unsigned char* ws = (unsigned char*)d_ws;
    moshi_convert<<<dim3(4096), dim3(256), 0, stream>>>(x, w, lidx, ws);
    // diagnostics first (their out-writes are fully overwritten by the real gemm)
    moshi_diag<1><<<dim3(72 * 16), dim3(256), 0, stream>>>(ws, out);
    moshi_diag<2><<<dim3(72 * 16), dim3(256), 0, stream>>>(ws, out);
    // real gemm: 72 pair slots x 16 n-tiles
    moshi_gemm_n64<<<dim3(72 * 16), dim3(256), 0, stream>>>(ws, out);
}

// Round 6
// 58.910 us; speedup vs baseline: 1.6202x; 1.6202x over previous
//
#include <hip/hip_runtime.h>
#include <hip/hip_bf16.h>

#define B_ 64
#define S_ 128
#define D_ 1024
#define O_ 1024
#define L_ 16

typedef __bf16 bf16x8 __attribute__((ext_vector_type(8)));
typedef float f32x4 __attribute__((ext_vector_type(4)));
typedef unsigned u32x4 __attribute__((ext_vector_type(4)));

// ws layout (bytes):
//  [0, 33554432)        W bf16, tiles [l][nt:8][kt:16], each 128(o) x 64(k) bf16 = 16384 B, XOR-swizzled
//  [33554432, 50331648) x bf16, tiles [s:128][kt:16], each 64(b) x 64(k) bf16 = 8192 B, XOR-swizzled
//  [50331648]           npairs (int, 16-byte slot)
//  [50331664, +72*16)   pairs int4 {s0, s1, layer, 0}
#define WS_W   0ull
#define WS_X   33554432ull
#define WS_P   50331648ull
#define WS_NEED (50331664ull + 72ull * 16ull)

__device__ __forceinline__ unsigned f2bf2(float a, float b) {
    union { float f; unsigned u; } x{a}, y{b};
    unsigned lo = x.u + 0x7FFFu + ((x.u >> 16) & 1u);
    unsigned hi = y.u + 0x7FFFu + ((y.u >> 16) & 1u);
    return (lo >> 16) | (hi & 0xFFFF0000u);
}

__device__ __forceinline__ void gload16(const void* g, void* l) {
    __builtin_amdgcn_global_load_lds(
        (const __attribute__((address_space(1))) void*)g,
        (__attribute__((address_space(3))) void*)l, 16, 0, 0);
}

// ---- pass 1: fp32 -> bf16 conversion into pre-swizzled tiles + pair build.
// 4x ILP: each thread handles 4 consecutive float4 (64 B in, 32 B out).
// The 32B output group is 32B-aligned pre-swizzle; the XOR key ((row&7)<<4)
// permutes 16B units, so store as two 16B halves at (c^k) and ((c+16)^k).
__global__ __launch_bounds__(256) void moshi_convert(
    const float* __restrict__ x, const float* __restrict__ w,
    const int* __restrict__ lidx, unsigned char* __restrict__ ws) {
    if (blockIdx.x == 0 && threadIdx.x < 16) {
        int t = threadIdx.x;
        int cnt[16];
        #pragma unroll 1
        for (int m = 0; m < 16; ++m) cnt[m] = 0;
        for (int s = 0; s < S_; ++s) ++cnt[lidx[s]];
        int off = 0;
        for (int m = 0; m < t; ++m) off += (cnt[m] + 1) >> 1;
        int4* pairs = (int4*)(ws + WS_P + 16);
        int k = 0, prev = -1;
        for (int s = 0; s < S_; ++s) {
            if (lidx[s] == t) {
                if (k & 1) pairs[off + (k >> 1)] = make_int4(prev, s, t, 0);
                prev = s; ++k;
            }
        }
        if (k & 1) pairs[off + (k >> 1)] = make_int4(prev, prev, t, 0);
        if (t == 0) {
            int tot = 0;
            for (int m = 0; m < 16; ++m) tot += (cnt[m] + 1) >> 1;
            *(int*)(ws + WS_P) = tot;
        }
    }
    const int TW4 = L_ * O_ * D_ / 16;   // 1048576 groups of 4 float4
    const int t0 = blockIdx.x * 256 + threadIdx.x;   // grid covers exactly TW4+TX4
    if (t0 < TW4) {
        const float4* src = reinterpret_cast<const float4*>(w) + 4ull * t0;
        float4 v0 = src[0], v1 = src[1], v2 = src[2], v3 = src[3];
        u32x4 lo = { f2bf2(v0.x, v0.y), f2bf2(v0.z, v0.w),
                     f2bf2(v1.x, v1.y), f2bf2(v1.z, v1.w) };
        u32x4 hi = { f2bf2(v2.x, v2.y), f2bf2(v2.z, v2.w),
                     f2bf2(v3.x, v3.y), f2bf2(v3.z, v3.w) };
        int f = t0 * 4;
        int d4 = f & 255, o = (f >> 8) & 1023, l = f >> 18;
        int nt = o >> 7, row = o & 127, kt = d4 >> 4;
        unsigned base = ((unsigned)((l * 8 + nt) * 16 + kt)) * 16384u + (unsigned)(row * 128);
        unsigned c = (unsigned)((d4 & 15) * 8);       // 0,32,64,96
        unsigned k = (unsigned)((row & 7) << 4);
        *reinterpret_cast<u32x4*>(ws + WS_W + base + (c ^ k))        = lo;
        *reinterpret_cast<u32x4*>(ws + WS_W + base + ((c + 16) ^ k)) = hi;
    } else {
        int g = (t0 - TW4) * 4;
        const float4* src = reinterpret_cast<const float4*>(x) + 4ull * (t0 - TW4);
        float4 v0 = src[0], v1 = src[1], v2 = src[2], v3 = src[3];
        u32x4 lo = { f2bf2(v0.x, v0.y), f2bf2(v0.z, v0.w),
                     f2bf2(v1.x, v1.y), f2bf2(v1.z, v1.w) };
        u32x4 hi = { f2bf2(v2.x, v2.y), f2bf2(v2.z, v2.w),
                     f2bf2(v3.x, v3.y), f2bf2(v3.z, v3.w) };
        int d4 = g & 255, s = (g >> 8) & 127, b = g >> 15;
        int kt = d4 >> 4;
        unsigned base = ((unsigned)(s * 16 + kt)) * 8192u + (unsigned)(b * 128);
        unsigned c = (unsigned)((d4 & 15) * 8);
        unsigned k = (unsigned)((b & 7) << 4);
        *reinterpret_cast<u32x4*>(ws + WS_X + base + (c ^ k))        = lo;
        *reinterpret_cast<u32x4*>(ws + WS_X + base + ((c + 16) ^ k)) = hi;
    }
}

// ---- pass 2: paired GEMM, tile M=128 (2s x 64b) x N=128, BK=64, 8 waves
// (2 wm x 4 wn), each wave 64x32 = 4x2 fragments — same per-wave inner loop
// as the R5 n64 kernel (which sustained ~12.6 TB/s staging) but 64 FLOP per
// staged byte instead of 43.7. Single-buffer 2-barrier loop, 32 KB LDS,
// grid 576, 18 waves/CU.
__global__ __launch_bounds__(512) void moshi_gemm_n128(
    const unsigned char* __restrict__ ws, float* __restrict__ out) {
    __shared__ __align__(16) unsigned char lw[16384];   // 128(o) x 64(k) bf16, swizzled
    __shared__ __align__(16) unsigned char lx[16384];   // s0:64 rows + s1:64 rows

    // bijective XCD-chunk swizzle: grid 576 = 8 chunks of 72 (9 pairs x 8 nt)
    const int bid = (blockIdx.x & 7) * 72 + (blockIdx.x >> 3);
    const int pi = bid >> 3;
    const int nt = bid & 7;
    const int np = *reinterpret_cast<const int*>(ws + WS_P);
    if (pi >= np) return;   // block-uniform exit before any barrier
    const int4 pr = *reinterpret_cast<const int4*>(ws + WS_P + 16 + 16ull * pi);
    const int s0 = pr.x, s1 = pr.y, l = pr.z;

    const unsigned char* wt  = ws + WS_W + ((size_t)(l * 8 + nt) * 16) * 16384;
    const unsigned char* xt0 = ws + WS_X + (size_t)s0 * 16 * 8192;
    const unsigned char* xt1 = ws + WS_X + (size_t)s1 * 16 * 8192;

    const int tid = threadIdx.x, lane = tid & 63, wid = tid >> 6;
    const int wm = wid >> 2, wn = wid & 3;
    const int swz = (lane & 7) << 4;
    const int kb  = (lane >> 4) << 4;
    const int a_base = (wm * 64 + (lane & 15)) * 128 + kb;   // x rows
    const int b_base = (wn * 32 + (lane & 15)) * 128 + kb;   // W rows

    f32x4 acc[4][2];
    #pragma unroll
    for (int i = 0; i < 4; ++i)
        #pragma unroll
        for (int j = 0; j < 2; ++j) acc[i][j] = (f32x4)0.0f;

    #pragma unroll 1
    for (int kt = 0; kt < 16; ++kt) {
        __syncthreads();
        // stage: 4 gloads/thread (512 thr x 16 B = 8 KB per pass)
        gload16(wt  + (size_t)kt * 16384 + tid * 16,        lw + tid * 16);
        gload16(wt  + (size_t)kt * 16384 + tid * 16 + 8192, lw + tid * 16 + 8192);
        gload16(xt0 + (size_t)kt * 8192  + tid * 16,        lx + tid * 16);
        gload16(xt1 + (size_t)kt * 8192  + tid * 16,        lx + tid * 16 + 8192);
        __syncthreads();
        #pragma unroll
        for (int kk = 0; kk < 2; ++kk) {
            bf16x8 af[4], bfr[2];
            #pragma unroll
            for (int mi = 0; mi < 4; ++mi)
                af[mi] = *reinterpret_cast<const bf16x8*>(
                    lx + (((a_base + kk * 64) ^ swz) + mi * 2048));
            #pragma unroll
            for (int ni = 0; ni < 2; ++ni)
                bfr[ni] = *reinterpret_cast<const bf16x8*>(
                    lw + (((b_base + kk * 64) ^ swz) + ni * 2048));
            #pragma unroll
            for (int mi = 0; mi < 4; ++mi)
                #pragma unroll
                for (int ni = 0; ni < 2; ++ni)
                    acc[mi][ni] = __builtin_amdgcn_mfma_f32_16x16x32_bf16(
                        af[mi], bfr[ni], acc[mi][ni], 0, 0, 0);
        }
    }

    // epilogue: C/D col = lane&15 (o), row = (lane>>4)*4 + reg (b)
    const int s_sel = wm ? s1 : s0;
    const int col0 = nt * 128 + wn * 32 + (lane & 15);
    const int r0 = (lane >> 4) << 2;
    #pragma unroll
    for (int mi = 0; mi < 4; ++mi)
        #pragma unroll
        for (int ni = 0; ni < 2; ++ni)
            #pragma unroll
            for (int r = 0; r < 4; ++r) {
                int b = mi * 16 + r0 + r;
                out[((size_t)b * S_ + s_sel) * O_ + col0 + ni * 16] = acc[mi][ni][r];
            }
}

// ---- fallback (round-1 kernel) if ws is too small ----
__global__ __launch_bounds__(256) void moshi_flin_fallback(
    const float* __restrict__ x, const int* __restrict__ lidx,
    const float* __restrict__ w, float* __restrict__ out) {
    __shared__ __align__(16) unsigned char lxs[64 * 128];
    __shared__ __align__(16) unsigned char lws[128 * 128];
    const int bid = blockIdx.x;
    const int s = bid >> 3, n0 = (bid & 7) << 7;
    const int tid = threadIdx.x, lane = tid & 63, wid = tid >> 6;
    const int idx = lidx[s];
    const float* wb = w + (size_t)idx * O_ * D_ + (size_t)n0 * D_;
    const float* xb = x + (size_t)s * D_;
    const int swz = (lane & 7) << 4;
    const int kb = (lane >> 4) << 4;
    const int a_base = (lane & 15) * 128 + kb;
    const int b_base = (wid * 32 + (lane & 15)) * 128 + kb;
    f32x4 acc[4][2];
    #pragma unroll
    for (int i = 0; i < 4; ++i)
        #pragma unroll
        for (int j = 0; j < 2; ++j) acc[i][j] = (f32x4)0.0f;
    for (int kt = 0; kt < D_; kt += 64) {
        __syncthreads();
        #pragma unroll
        for (int p = 0; p < 4; ++p) {
            int f = tid + p * 256, row = f >> 4, cc = (f & 15) << 2;
            const float4 v = *reinterpret_cast<const float4*>(
                xb + (size_t)row * (S_ * D_) + kt + cc);
            uint2 pk = { f2bf2(v.x, v.y), f2bf2(v.z, v.w) };
            *reinterpret_cast<uint2*>(&lxs[(row * 128 + cc * 2) ^ ((row & 7) << 4)]) = pk;
        }
        #pragma unroll
        for (int p = 0; p < 8; ++p) {
            int f = tid + p * 256, row = f >> 4, cc = (f & 15) << 2;
            const float4 v = *reinterpret_cast<const float4*>(
                wb + (size_t)row * D_ + kt + cc);
            uint2 pk = { f2bf2(v.x, v.y), f2bf2(v.z, v.w) };
            *reinterpret_cast<uint2*>(&lws[(row * 128 + cc * 2) ^ ((row & 7) << 4)]) = pk;
        }
        __syncthreads();
        #pragma unroll
        for (int kk = 0; kk < 2; ++kk) {
            bf16x8 af[4], bfr[2];
            #pragma unroll
            for (int mi = 0; mi < 4; ++mi)
                af[mi] = *reinterpret_cast<const bf16x8*>(
                    &lxs[(((a_base + kk * 64) ^ swz) + mi * 2048)]);
            #pragma unroll
            for (int ni = 0; ni < 2; ++ni)
                bfr[ni] = *reinterpret_cast<const bf16x8*>(
                    &lws[(((b_base + kk * 64) ^ swz) + ni * 2048)]);
            #pragma unroll
            for (int mi = 0; mi < 4; ++mi)
                #pragma unroll
                for (int ni = 0; ni < 2; ++ni)
                    acc[mi][ni] = __builtin_amdgcn_mfma_f32_16x16x32_bf16(
                        af[mi], bfr[ni], acc[mi][ni], 0, 0, 0);
        }
    }
    float* ob = out + (size_t)s * O_ + n0 + wid * 32 + (lane & 15);
    const int r0 = (lane >> 4) << 2;
    #pragma unroll
    for (int mi = 0; mi < 4; ++mi)
        #pragma unroll
        for (int ni = 0; ni < 2; ++ni)
            #pragma unroll
            for (int r = 0; r < 4; ++r) {
                int b = mi * 16 + r0 + r;
                ob[(size_t)b * (S_ * O_) + ni * 16] = acc[mi][ni][r];
            }
}

extern "C" void kernel_launch(void* const* d_in, const int* in_sizes, int n_in,
                              void* d_out, int out_size, void* d_ws, size_t ws_size,
                              hipStream_t stream) {
    const float* x  = (const float*)d_in[0];
    const int* lidx = (const int*)d_in[1];
    const float* w  = (const float*)d_in[2];
    float* out      = (float*)d_out;

    if (ws_size < WS_NEED) {
        moshi_flin_fallback<<<dim3(128 * 8), dim3(256), 0, stream>>>(x, lidx, w, out);
        return;
    }
    unsigned char* ws = (unsigned char*)d_ws;
    // (TW+TX)/16 threads = 1572864 -> 6144 blocks of 256, one group-of-4 each
    moshi_convert<<<dim3(6144), dim3(256), 0, stream>>>(x, w, lidx, ws);
    // 72 pair slots x 8 n-tiles, 512 threads
    moshi_gemm_n128<<<dim3(72 * 8), dim3(512), 0, stream>>>(ws, out);
}